// Round 3
// baseline (898.367 us; speedup 1.0000x reference)
//
#include <hip/hip_runtime.h>
#include <hip/hip_bf16.h>

typedef unsigned long long u64;
typedef unsigned int u32;
typedef unsigned short u16;
typedef __attribute__((ext_vector_type(4))) float f32x4v;
typedef __attribute__((ext_vector_type(16))) float f32x16;
typedef __attribute__((ext_vector_type(8))) short bf16x8;  // 8 bf16 in 4 VGPRs

#define N_NODES 20000
#define N_EDGES 5000
#define FT 128
#define NT 20             // 256-col tiles per row in scan
#define NRG 313           // 64-row groups (last = 32 rows)
#define ROW_U64 80        // Hbt[n][w]: PLAIN bits, bit b <-> edge 64w+b
#define COL_STRIDE 5120   // HbtT[w][e]: bit b <-> node 64w+b (plain in n)
#define XWT_S 20032       // XwT row stride (20000 padded to 64-lane multiple)

#define NTLOAD(p) __builtin_nontemporal_load((const f32x4v*)(p))

static __device__ __forceinline__ u64 spread4(u64 x) {  // bit i -> bit 4i (i<16)
  x = (x | (x << 24)) & 0x000000FF000000FFull;
  x = (x | (x << 12)) & 0x000F000F000F000Full;
  x = (x | (x << 6))  & 0x0303030303030303ull;
  x = (x | (x << 3))  & 0x1111111111111111ull;
  return x;
}

static __device__ __forceinline__ u16 f2bf(float x) {   // f32 -> bf16 rn
  u32 u = __float_as_uint(x);
  u = (u + 0x7FFFu + ((u >> 16) & 1u)) >> 16;
  return (u16)u;
}

// expand 8 H-bits -> 8 bf16 {0.0, 1.0}; element j <-> bit j
static __device__ __forceinline__ bf16x8 expand8(u32 b) {
  union { u32 u[4]; bf16x8 v; } r;
  r.u[0] = (( b        & 1u) | ((( b >> 1) & 1u) << 16)) * 0x3F80u;
  r.u[1] = (((b >> 2)  & 1u) | ((( b >> 3) & 1u) << 16)) * 0x3F80u;
  r.u[2] = (((b >> 4)  & 1u) | ((( b >> 5) & 1u) << 16)) * 0x3F80u;
  r.u[3] = (((b >> 6)  & 1u) | ((( b >> 7) & 1u) << 16)) * 0x3F80u;
  return r.v;
}

// ---------------------------------------------------------------------------
// Pass 1: NT-load ballot scan of H -> plain row bitmask Hbt (de-interleaved
// in-register via bit-spread) + plain-in-n column bitmask HbtT (in-wave 64x64
// transpose), with X->bf16 and W->bf16-transpose folded into tail blocks.
__global__ __launch_bounds__(256) void scan_fused(
    const float* __restrict__ H, u64* __restrict__ Hbt, u64* __restrict__ HbtT,
    const float2* __restrict__ X2, __hip_bfloat162* __restrict__ Xb2,
    const float* __restrict__ Wf, u16* __restrict__ WtB) {
  const int wid = threadIdx.x >> 6, lane = threadIdx.x & 63;

  if (blockIdx.x >= 1565) {                    // folded tails
    for (int i = (blockIdx.x - 1565) * 256 + threadIdx.x; i < 1280000;
         i += 320 * 256)
      Xb2[i] = __float22bfloat162_rn(X2[i]);
    if (blockIdx.x == 1884) {                  // WtB[f][k] = bf16(W[k][f])
      for (int i = threadIdx.x; i < FT * FT; i += 256) {
        int f = i >> 7, k = i & 127;
        WtB[i] = f2bf(Wf[k * FT + f]);
      }
    }
    return;
  }

  const int gw = blockIdx.x * 4 + wid;         // 1565*4 = 6260 = NRG*NT
  const int t = gw % NT, rg = gw / NT;
  const int r0 = rg * 64;
  const int rows = min(64, N_NODES - r0);
  const int idx4 = t * 64 + lane;
  const bool lv = idx4 < 1250;

  u64 m0 = 0, m1 = 0, m2 = 0, m3 = 0;         // lane i: row r0+i, cols 256t+4l+c
  for (int kb = 0; kb < rows; kb += 8) {
    f32x4v vv[8];
#pragma unroll
    for (int k = 0; k < 8; ++k) vv[k] = (f32x4v){0.f, 0.f, 0.f, 0.f};
    if (lv) {
      const float* bp = H + (size_t)(r0 + kb) * N_EDGES + idx4 * 4;
#pragma unroll
      for (int k = 0; k < 8; ++k) vv[k] = NTLOAD(bp + (size_t)k * N_EDGES);
    }
#pragma unroll
    for (int k = 0; k < 8; ++k) {
      u64 b0 = __ballot(vv[k].x != 0.f);
      u64 b1 = __ballot(vv[k].y != 0.f);
      u64 b2 = __ballot(vv[k].z != 0.f);
      u64 b3 = __ballot(vv[k].w != 0.f);
      const bool keep = (lane == kb + k);
      m0 = keep ? b0 : m0;  m1 = keep ? b1 : m1;
      m2 = keep ? b2 : m2;  m3 = keep ? b3 : m3;
    }
  }
  // de-interleave -> plain words: word j covers edges 256t+64j+b,
  // bit b from m[b&3] bit (16j + (b>>2)).
  if (lane < rows) {
    u64* hp = Hbt + (size_t)(r0 + lane) * ROW_U64 + t * 4;
#pragma unroll
    for (int j = 0; j < 4; ++j) {
      u64 p = spread4((m0 >> (16 * j)) & 0xFFFFull)
            | (spread4((m1 >> (16 * j)) & 0xFFFFull) << 1)
            | (spread4((m2 >> (16 * j)) & 0xFFFFull) << 2)
            | (spread4((m3 >> (16 * j)) & 0xFFFFull) << 3);
      hp[j] = p;
    }
  }
  // in-wave 64x64 bit transpose -> column masks (bit i <-> row r0+i, plain)
  u64 t0 = 0, t1 = 0, t2 = 0, t3 = 0;
  for (int l = 0; l < 64; ++l) {
    u64 c0 = __ballot((m0 >> l) & 1ull);
    u64 c1 = __ballot((m1 >> l) & 1ull);
    u64 c2 = __ballot((m2 >> l) & 1ull);
    u64 c3 = __ballot((m3 >> l) & 1ull);
    const bool keep = (lane == l);
    t0 = keep ? c0 : t0;  t1 = keep ? c1 : t1;
    t2 = keep ? c2 : t2;  t3 = keep ? c3 : t3;
  }
  // column-indexed store: HbtT[w][col], col = 256t + 4*lane + c
  u64* op = HbtT + (size_t)rg * COL_STRIDE + t * 256 + 4 * lane;
  op[0] = t0; op[1] = t1; op[2] = t2; op[3] = t3;
}

// ---------------------------------------------------------------------------
// Pass 2: XwT[f][n] = bf16( (X @ W)[n][f] ).  MFMA 32x32x16: m=f, n=node,
// k=in-feat. A = WtB[f][k], B = Xb[n][k] (both 16B/lane, same k-mapping so
// any HW k-permutation cancels). Block 625 zeroes the n-pad [20000,20032).
__global__ __launch_bounds__(256) void gemm_xw(
    const u16* __restrict__ Xb, const u16* __restrict__ WtB,
    u16* __restrict__ XwT) {
  const int wave = threadIdx.x >> 6, lane = threadIdx.x & 63;
  const int col = lane & 31, half = lane >> 5;
  const int n0 = blockIdx.x * 32;
  const int f0 = wave * 32;
  if (n0 >= N_NODES) {                         // zero the pad columns
    if (lane < 32)
      for (int r = 0; r < 32; ++r)
        XwT[(size_t)(f0 + r) * XWT_S + n0 + lane] = 0;
    return;
  }
  f32x16 acc;
#pragma unroll
  for (int i = 0; i < 16; ++i) acc[i] = 0.f;
  for (int k0 = 0; k0 < FT; k0 += 16) {
    bf16x8 a = *(const bf16x8*)(WtB + (f0 + col) * FT + k0 + half * 8);
    bf16x8 b = *(const bf16x8*)(Xb + (size_t)(n0 + col) * FT + k0 + half * 8);
    acc = __builtin_amdgcn_mfma_f32_32x32x16_bf16(a, b, acc, 0, 0, 0);
  }
#pragma unroll
  for (int r = 0; r < 16; ++r) {
    int fr = (r & 3) + 8 * (r >> 2) + 4 * half;   // D row (verified map)
    XwT[(size_t)(f0 + fr) * XWT_S + n0 + col] = f2bf(acc[r]);
  }
}

// ---------------------------------------------------------------------------
// Pass 3: MhT[f][e] = bf16( sum_n Xw[n][f]*H[n][e] / (DE[e]+1e-12) ).
// MFMA 32x32x16: m=f, n=edge, k=node-bits expanded from HbtT words.
// Full-K per block (no partials -> no Mpart buffer). Grid 160 = 80 e-tiles
// x 2 f-halves; each wave owns one 32x32 (f,e) tile. DE via popcount.
__global__ __launch_bounds__(256) void edge_gemm(
    const u16* __restrict__ XwT, const u64* __restrict__ HbtT,
    u16* __restrict__ MhT) {
  const int wave = threadIdx.x >> 6, lane = threadIdx.x & 63;
  const int col = lane & 31, half = lane >> 5;
  const int et = blockIdx.x >> 1, fg = blockIdx.x & 1;
  const int e0 = et * 64 + (wave >> 1) * 32;
  const int f0 = fg * 64 + (wave & 1) * 32;

  f32x16 acc;
#pragma unroll
  for (int i = 0; i < 16; ++i) acc[i] = 0.f;
  float dv = 0.f;

  for (int w = 0; w < NRG; ++w) {
    u64 wd = HbtT[(size_t)w * COL_STRIDE + e0 + col];
    dv += (float)__popcll(wd);
    const u16* abase = XwT + (size_t)(f0 + col) * XWT_S + w * 64 + half * 8;
#pragma unroll
    for (int q = 0; q < 4; ++q) {
      bf16x8 a = *(const bf16x8*)(abase + q * 16);
      bf16x8 b = expand8((u32)(wd >> (q * 16 + half * 8)) & 0xFFu);
      acc = __builtin_amdgcn_mfma_f32_32x32x16_bf16(a, b, acc, 0, 0, 0);
    }
  }
  float inv = 1.f / (dv + 1e-12f);             // per-lane: col <-> edge
#pragma unroll
  for (int r = 0; r < 16; ++r) {
    int fr = f0 + (r & 3) + 8 * (r >> 2) + 4 * half;
    MhT[(size_t)fr * COL_STRIDE + e0 + col] = f2bf(acc[r] * inv);
  }
}

// ---------------------------------------------------------------------------
// Pass 4: out[n][f] = relu( (H @ M)[n][f] / DV[n] + bias[f] ).
// MFMA 32x32x16: m=node, n=feat, k=edge-bits from LDS-staged Hbt words.
__global__ __launch_bounds__(256) void node_gemm(
    const u64* __restrict__ Hbt, const u16* __restrict__ MhT,
    const float* __restrict__ bias, float* __restrict__ out) {
  __shared__ u64 ld[32][81];                   // +1 pad -> 2-way bank (free)
  const int tid = threadIdx.x;
  const int wave = tid >> 6, lane = tid & 63;
  const int col = lane & 31, half = lane >> 5;
  const int n0 = blockIdx.x * 32;
  {
    int r = tid & 31, g = tid >> 5;            // 8 groups x 10 words
#pragma unroll
    for (int i = 0; i < 10; ++i)
      ld[r][g * 10 + i] = Hbt[(size_t)(n0 + r) * ROW_U64 + g * 10 + i];
  }
  __syncthreads();
  const int f0 = wave * 32;
  f32x16 acc;
#pragma unroll
  for (int i = 0; i < 16; ++i) acc[i] = 0.f;
  float dv = 0.f;
  for (int w = 0; w < ROW_U64; ++w) {
    u64 word = ld[col][w];
    if (half == 0) dv += (float)__popcll(word);
    const u16* bbase = MhT + (size_t)(f0 + col) * COL_STRIDE + w * 64 + half * 8;
#pragma unroll
    for (int q = 0; q < 4; ++q) {
      bf16x8 afrag = expand8((u32)(word >> (q * 16 + half * 8)) & 0xFFu);
      bf16x8 bfrag = *(const bf16x8*)(bbase + q * 16);
      acc = __builtin_amdgcn_mfma_f32_32x32x16_bf16(afrag, bfrag, acc, 0, 0, 0);
    }
  }
  float inv = 1.f / (dv + 1e-12f);             // valid in lanes 0..31 (row=lane)
  float bb = bias[f0 + col];
#pragma unroll
  for (int r = 0; r < 16; ++r) {
    int rr = (r & 3) + 8 * (r >> 2) + 4 * half;    // D row = node-local
    float iv = __shfl(inv, rr);
    float o = fmaxf(fmaf(acc[r], iv, bb), 0.f);
    out[(size_t)(n0 + rr) * FT + f0 + col] = o;
  }
}

extern "C" void kernel_launch(void* const* d_in, const int* in_sizes, int n_in,
                              void* d_out, int out_size, void* d_ws, size_t ws_size,
                              hipStream_t stream) {
  const float* X    = (const float*)d_in[0];   // [20000, 128]
  const float* H    = (const float*)d_in[1];   // [20000, 5000] dense 0/1
  const float* W    = (const float*)d_in[2];   // [128, 128]
  const float* bias = (const float*)d_in[3];   // [128]
  float* out = (float*)d_out;                  // [20000, 128] fp32

  // Workspace (int units), 35.9 MB total (<= proven 36.2 MB footprint).
  // MhT aliases Xb2: Xb2's last read is gemm_xw (dispatch 2); MhT's first
  // write is edge_gemm (dispatch 3). Every read location is written first.
  int* ws = (int*)d_ws;
  u64* Hbt             = (u64*)ws;                          // 1,600,000 u64
  u64* HbtT            = (u64*)(ws + 3200000);              // 313*5120 u64
  __hip_bfloat162* Xb2 = (__hip_bfloat162*)(ws + 6405120);  // 1,280,000 ints
  u16* MhT             = (u16*)(ws + 6405120);              // 128*5120 bf16 (alias)
  u16* WtB             = (u16*)(ws + 7685120);              // 16,384 bf16
  u16* XwT             = (u16*)(ws + 7693312);              // 128*20032 bf16
  // end: 8,975,360 ints = 35.9 MB

  scan_fused<<<1885, 256, 0, stream>>>(H, Hbt, HbtT, (const float2*)X, Xb2,
                                       W, WtB);
  gemm_xw   <<<626, 256, 0, stream>>>((const u16*)Xb2, WtB, XwT);
  edge_gemm <<<160, 256, 0, stream>>>(XwT, HbtT, MhT);
  node_gemm <<<625, 256, 0, stream>>>(Hbt, MhT, bias, out);
}

// Round 4
// 718.993 us; speedup vs baseline: 1.2495x; 1.2495x over previous
//
#include <hip/hip_runtime.h>
#include <hip/hip_bf16.h>

typedef unsigned long long u64;
typedef unsigned int u32;
typedef unsigned short u16;
typedef __attribute__((ext_vector_type(4))) float f32x4v;
typedef __attribute__((ext_vector_type(16))) float f32x16;
typedef __attribute__((ext_vector_type(8))) short bf16x8;  // 8 bf16 in 4 VGPRs

#define N_NODES 20000
#define N_EDGES 5000
#define FT 128
#define NT 20             // 256-col tiles per row in scan
#define NRG 313           // 64-row groups (last = 32 rows)
#define ROW_U64 80        // Hbt[n][w]: PLAIN bits, bit b <-> edge 64w+b
#define COL_STRIDE 5120   // HbtT[w][e]: bit b <-> node 64w+b (plain in n)
#define XWT_S 20032       // XwT row stride (20000 padded)

#define NTLOAD(p) __builtin_nontemporal_load((const f32x4v*)(p))

static __device__ __forceinline__ u64 spread4(u64 x) {  // bit i -> bit 4i (i<16)
  x = (x | (x << 24)) & 0x000000FF000000FFull;
  x = (x | (x << 12)) & 0x000F000F000F000Full;
  x = (x | (x << 6))  & 0x0303030303030303ull;
  x = (x | (x << 3))  & 0x1111111111111111ull;
  return x;
}

static __device__ __forceinline__ u16 f2bf(float x) {   // f32 -> bf16 rn
  u32 u = __float_as_uint(x);
  u = (u + 0x7FFFu + ((u >> 16) & 1u)) >> 16;
  return (u16)u;
}

// expand 8 H-bits -> 8 bf16 {0.0, 1.0}; element j <-> bit j
static __device__ __forceinline__ bf16x8 expand8(u32 b) {
  union { u32 u[4]; bf16x8 v; } r;
  r.u[0] = (( b        & 1u) | ((( b >> 1) & 1u) << 16)) * 0x3F80u;
  r.u[1] = (((b >> 2)  & 1u) | ((( b >> 3) & 1u) << 16)) * 0x3F80u;
  r.u[2] = (((b >> 4)  & 1u) | ((( b >> 5) & 1u) << 16)) * 0x3F80u;
  r.u[3] = (((b >> 6)  & 1u) | ((( b >> 7) & 1u) << 16)) * 0x3F80u;
  return r.v;
}

// ---------------------------------------------------------------------------
// Pass 1: NT-load ballot scan of H -> plain row bitmask Hbt + plain column
// bitmask HbtT, X->bf16 and W->bf16-transpose folded into tails. UNCHANGED.
__global__ __launch_bounds__(256) void scan_fused(
    const float* __restrict__ H, u64* __restrict__ Hbt, u64* __restrict__ HbtT,
    const float2* __restrict__ X2, __hip_bfloat162* __restrict__ Xb2,
    const float* __restrict__ Wf, u16* __restrict__ WtB) {
  const int wid = threadIdx.x >> 6, lane = threadIdx.x & 63;

  if (blockIdx.x >= 1565) {                    // folded tails
    for (int i = (blockIdx.x - 1565) * 256 + threadIdx.x; i < 1280000;
         i += 320 * 256)
      Xb2[i] = __float22bfloat162_rn(X2[i]);
    if (blockIdx.x == 1884) {                  // WtB[f][k] = bf16(W[k][f])
      for (int i = threadIdx.x; i < FT * FT; i += 256) {
        int f = i >> 7, k = i & 127;
        WtB[i] = f2bf(Wf[k * FT + f]);
      }
    }
    return;
  }

  const int gw = blockIdx.x * 4 + wid;         // 1565*4 = 6260 = NRG*NT
  const int t = gw % NT, rg = gw / NT;
  const int r0 = rg * 64;
  const int rows = min(64, N_NODES - r0);
  const int idx4 = t * 64 + lane;
  const bool lv = idx4 < 1250;

  u64 m0 = 0, m1 = 0, m2 = 0, m3 = 0;
  for (int kb = 0; kb < rows; kb += 8) {
    f32x4v vv[8];
#pragma unroll
    for (int k = 0; k < 8; ++k) vv[k] = (f32x4v){0.f, 0.f, 0.f, 0.f};
    if (lv) {
      const float* bp = H + (size_t)(r0 + kb) * N_EDGES + idx4 * 4;
#pragma unroll
      for (int k = 0; k < 8; ++k) vv[k] = NTLOAD(bp + (size_t)k * N_EDGES);
    }
#pragma unroll
    for (int k = 0; k < 8; ++k) {
      u64 b0 = __ballot(vv[k].x != 0.f);
      u64 b1 = __ballot(vv[k].y != 0.f);
      u64 b2 = __ballot(vv[k].z != 0.f);
      u64 b3 = __ballot(vv[k].w != 0.f);
      const bool keep = (lane == kb + k);
      m0 = keep ? b0 : m0;  m1 = keep ? b1 : m1;
      m2 = keep ? b2 : m2;  m3 = keep ? b3 : m3;
    }
  }
  if (lane < rows) {                           // de-interleave -> plain words
    u64* hp = Hbt + (size_t)(r0 + lane) * ROW_U64 + t * 4;
#pragma unroll
    for (int j = 0; j < 4; ++j) {
      u64 p = spread4((m0 >> (16 * j)) & 0xFFFFull)
            | (spread4((m1 >> (16 * j)) & 0xFFFFull) << 1)
            | (spread4((m2 >> (16 * j)) & 0xFFFFull) << 2)
            | (spread4((m3 >> (16 * j)) & 0xFFFFull) << 3);
      hp[j] = p;
    }
  }
  u64 t0 = 0, t1 = 0, t2 = 0, t3 = 0;          // 64x64 bit transpose
  for (int l = 0; l < 64; ++l) {
    u64 c0 = __ballot((m0 >> l) & 1ull);
    u64 c1 = __ballot((m1 >> l) & 1ull);
    u64 c2 = __ballot((m2 >> l) & 1ull);
    u64 c3 = __ballot((m3 >> l) & 1ull);
    const bool keep = (lane == l);
    t0 = keep ? c0 : t0;  t1 = keep ? c1 : t1;
    t2 = keep ? c2 : t2;  t3 = keep ? c3 : t3;
  }
  u64* op = HbtT + (size_t)rg * COL_STRIDE + t * 256 + 4 * lane;
  op[0] = t0; op[1] = t1; op[2] = t2; op[3] = t3;
}

// ---------------------------------------------------------------------------
// Pass 2: XwT[f][n] = bf16( (X @ W)[n][f] ). UNCHANGED (proven).
__global__ __launch_bounds__(256) void gemm_xw(
    const u16* __restrict__ Xb, const u16* __restrict__ WtB,
    u16* __restrict__ XwT) {
  const int wave = threadIdx.x >> 6, lane = threadIdx.x & 63;
  const int col = lane & 31, half = lane >> 5;
  const int n0 = blockIdx.x * 32;
  const int f0 = wave * 32;
  if (n0 >= N_NODES) {                         // zero the pad columns
    if (lane < 32)
      for (int r = 0; r < 32; ++r)
        XwT[(size_t)(f0 + r) * XWT_S + n0 + lane] = 0;
    return;
  }
  f32x16 acc;
#pragma unroll
  for (int i = 0; i < 16; ++i) acc[i] = 0.f;
  for (int k0 = 0; k0 < FT; k0 += 16) {
    bf16x8 a = *(const bf16x8*)(WtB + (f0 + col) * FT + k0 + half * 8);
    bf16x8 b = *(const bf16x8*)(Xb + (size_t)(n0 + col) * FT + k0 + half * 8);
    acc = __builtin_amdgcn_mfma_f32_32x32x16_bf16(a, b, acc, 0, 0, 0);
  }
#pragma unroll
  for (int r = 0; r < 16; ++r) {
    int fr = (r & 3) + 8 * (r >> 2) + 4 * half;
    XwT[(size_t)(f0 + fr) * XWT_S + n0 + col] = f2bf(acc[r]);
  }
}

// ---------------------------------------------------------------------------
// Pass 3: MhT[f][e] = bf16( sum_n Xw[n][f]*H[n][e] / DE[e] ).
// Grid 320 = 80 e-tiles(64) x 4 f-tiles(32). Waves k-split the 313 words
// {79,78,78,78}; per-wave double-buffered A-tile in LDS (barrier-free loop);
// B via 4KB expand-LUT (mostly-broadcast ds_read); cross-wave LDS reduce.
__global__ __launch_bounds__(256) void edge_gemm(
    const u16* __restrict__ XwT, const u64* __restrict__ HbtT,
    u16* __restrict__ MhT) {
  __shared__ bf16x8 lut[256];        // 4 KB expand table
  __shared__ u16 atile[4][2][2048];  // 32 KB: per-wave dbuf [chunk8][row32]
  __shared__ float sdv[4][64];       // partial DE per wave
  const int tid = threadIdx.x;
  const int wid = tid >> 6, lane = tid & 63;
  const int col = lane & 31, half = lane >> 5;
  lut[tid] = expand8((u32)tid);
  __syncthreads();

  const int et = blockIdx.x % 80, ft = blockIdx.x / 80;
  const int e0 = et * 64, f0 = ft * 32;
  const int ws_ = wid * 78 + (wid > 0 ? 1 : 0);       // 0,79,157,235
  const int we_ = ws_ + (wid == 0 ? 79 : 78);         // 79,157,235,313

  // stage: instr j covers rows 8j..8j+7 fully coalesced (8 lanes/row)
  const int srow = lane >> 3, schunk = lane & 7;
  const u16* sgbase = XwT + (size_t)(f0 + srow) * XWT_S + schunk * 8;
  u16* buf0 = &atile[wid][0][0];
  u16* buf1 = &atile[wid][1][0];

  f32x16 acc0, acc1;
#pragma unroll
  for (int i = 0; i < 16; ++i) { acc0[i] = 0.f; acc1[i] = 0.f; }
  float dvA = 0.f, dvB = 0.f;

  {                                            // prologue: stage w=ws_
    bf16x8 st[4];
#pragma unroll
    for (int j = 0; j < 4; ++j)
      st[j] = *(const bf16x8*)(sgbase + (size_t)(8 * j) * XWT_S + ws_ * 64);
#pragma unroll
    for (int j = 0; j < 4; ++j)
      *(bf16x8*)(buf0 + schunk * 256 + (8 * j + srow) * 8) = st[j];
  }
  u64 wA = HbtT[(size_t)ws_ * COL_STRIDE + e0 + col];
  u64 wB = HbtT[(size_t)ws_ * COL_STRIDE + e0 + 32 + col];

  int p = 0;
  for (int w = ws_; w < we_; ++w) {
    const int wn = (w + 1 < we_) ? w + 1 : w;
    bf16x8 nst[4];                             // prefetch next tile to regs
#pragma unroll
    for (int j = 0; j < 4; ++j)
      nst[j] = *(const bf16x8*)(sgbase + (size_t)(8 * j) * XWT_S + wn * 64);
    u64 nA = HbtT[(size_t)wn * COL_STRIDE + e0 + col];
    u64 nB = HbtT[(size_t)wn * COL_STRIDE + e0 + 32 + col];

    const u16* ab = p ? buf1 : buf0;           // compute current
#pragma unroll
    for (int q = 0; q < 4; ++q) {
      bf16x8 a  = *(const bf16x8*)(ab + (2 * q + half) * 256 + col * 8);
      bf16x8 bA = lut[(wA >> (q * 16 + half * 8)) & 0xFF];
      bf16x8 bB = lut[(wB >> (q * 16 + half * 8)) & 0xFF];
      acc0 = __builtin_amdgcn_mfma_f32_32x32x16_bf16(a, bA, acc0, 0, 0, 0);
      acc1 = __builtin_amdgcn_mfma_f32_32x32x16_bf16(a, bB, acc1, 0, 0, 0);
    }
    dvA += (float)__popcll(wA);
    dvB += (float)__popcll(wB);

    u16* nb = p ? buf0 : buf1;                 // write-late (T14)
#pragma unroll
    for (int j = 0; j < 4; ++j)
      *(bf16x8*)(nb + schunk * 256 + (8 * j + srow) * 8) = nst[j];
    wA = nA; wB = nB; p ^= 1;
  }

  // dump accs into own atile region (reused as 2048-f32 scratch per wave)
  float* sacc = (float*)&atile[wid][0][0];
#pragma unroll
  for (int r = 0; r < 16; ++r) {
    int fr = (r & 3) + 8 * (r >> 2) + 4 * half;
    sacc[fr * 64 + col]      = acc0[r];
    sacc[fr * 64 + 32 + col] = acc1[r];
  }
  if (half == 0) { sdv[wid][col] = dvA; sdv[wid][col + 32] = dvB; }
  __syncthreads();

  {                                            // cross-wave reduce + /DE + bf16
    const int frl = tid >> 3, el = (tid & 7) * 8;
    const float* s0 = (const float*)&atile[0][0][0];
    union { u16 h[8]; f32x4v v; } o;
#pragma unroll
    for (int j = 0; j < 8; ++j) {
      int idx = frl * 64 + el + j;
      float s = s0[idx] + s0[2048 + idx] + s0[4096 + idx] + s0[6144 + idx];
      float d = sdv[0][el + j] + sdv[1][el + j] + sdv[2][el + j] + sdv[3][el + j];
      o.h[j] = f2bf(s / (d + 1e-12f));
    }
    *(f32x4v*)(MhT + (size_t)(f0 + frl) * COL_STRIDE + e0 + el) = o.v;
  }
}

// ---------------------------------------------------------------------------
// Pass 4: out[n][f] = relu( (H @ M)[n][f] / DV[n] + bias[f] ).
// Grid 313 x (64 nodes x 128 f). Shared MhT e-slice [chunk8][row128] staged
// double-buffered (one barrier/iter); H-words software-prefetched; A via LUT.
__global__ __launch_bounds__(256) void node_gemm(
    const u64* __restrict__ Hbt, const u16* __restrict__ MhT,
    const float* __restrict__ bias, float* __restrict__ out) {
  __shared__ bf16x8 lut[256];        // 4 KB
  __shared__ u16 btile[2][8192];     // 32 KB dbuf
  const int tid = threadIdx.x;
  const int wid = tid >> 6, lane = tid & 63;
  const int col = lane & 31, half = lane >> 5;
  lut[tid] = expand8((u32)tid);

  const int n0 = blockIdx.x * 64;
  const int ns = wid & 1, fs = wid >> 1;
  const int f0 = fs * 64;
  const int myn = n0 + ns * 32 + col;
  const size_t arow = (size_t)min(myn, N_NODES - 1) * ROW_U64;

  // stage: instr j: row = 32j + (tid>>3), chunk = tid&7 (8 lanes/row, coalesced)
  const int srow = tid >> 3, schunk = tid & 7;
  const u16* sgbase = MhT + (size_t)srow * COL_STRIDE + schunk * 8;

  {                                            // prologue: stage w=0
    bf16x8 st[4];
#pragma unroll
    for (int j = 0; j < 4; ++j)
      st[j] = *(const bf16x8*)(sgbase + (size_t)(32 * j) * COL_STRIDE);
#pragma unroll
    for (int j = 0; j < 4; ++j)
      *(bf16x8*)(&btile[0][0] + schunk * 1024 + (32 * j + srow) * 8) = st[j];
  }
  u64 word = Hbt[arow];
  __syncthreads();

  f32x16 acc0, acc1;
#pragma unroll
  for (int i = 0; i < 16; ++i) { acc0[i] = 0.f; acc1[i] = 0.f; }
  float dv = 0.f;

  int p = 0;
  for (int w = 0; w < ROW_U64; ++w) {
    const int wn = (w + 1 < ROW_U64) ? w + 1 : w;
    bf16x8 nst[4];                             // prefetch next e-slice
#pragma unroll
    for (int j = 0; j < 4; ++j)
      nst[j] = *(const bf16x8*)(sgbase + (size_t)(32 * j) * COL_STRIDE + wn * 64);
    u64 nword = Hbt[arow + wn];

    const u16* bb = &btile[p][0];              // compute current
#pragma unroll
    for (int q = 0; q < 4; ++q) {
      bf16x8 a  = lut[(word >> (q * 16 + half * 8)) & 0xFF];
      bf16x8 b0 = *(const bf16x8*)(bb + (2 * q + half) * 1024 + (f0 + col) * 8);
      bf16x8 b1 = *(const bf16x8*)(bb + (2 * q + half) * 1024 + (f0 + 32 + col) * 8);
      acc0 = __builtin_amdgcn_mfma_f32_32x32x16_bf16(a, b0, acc0, 0, 0, 0);
      acc1 = __builtin_amdgcn_mfma_f32_32x32x16_bf16(a, b1, acc1, 0, 0, 0);
    }
    dv += (float)__popcll(word);

    u16* nb = &btile[p ^ 1][0];                // write-late into other buffer
#pragma unroll
    for (int j = 0; j < 4; ++j)
      *(bf16x8*)(nb + schunk * 1024 + (32 * j + srow) * 8) = nst[j];
    __syncthreads();
    word = nword; p ^= 1;
  }

  float inv = 1.f / (dv + 1e-12f);
  float bb0 = bias[f0 + col], bb1 = bias[f0 + 32 + col];
#pragma unroll
  for (int r = 0; r < 16; ++r) {
    int rr = (r & 3) + 8 * (r >> 2) + 4 * half;    // D row = node-local
    float iv = __shfl(inv, rr);
    int node = n0 + ns * 32 + rr;
    if (node < N_NODES) {
      out[(size_t)node * FT + f0 + col]      = fmaxf(fmaf(acc0[r], iv, bb0), 0.f);
      out[(size_t)node * FT + f0 + 32 + col] = fmaxf(fmaf(acc1[r], iv, bb1), 0.f);
    }
  }
}

extern "C" void kernel_launch(void* const* d_in, const int* in_sizes, int n_in,
                              void* d_out, int out_size, void* d_ws, size_t ws_size,
                              hipStream_t stream) {
  const float* X    = (const float*)d_in[0];   // [20000, 128]
  const float* H    = (const float*)d_in[1];   // [20000, 5000] dense 0/1
  const float* W    = (const float*)d_in[2];   // [128, 128]
  const float* bias = (const float*)d_in[3];   // [128]
  float* out = (float*)d_out;                  // [20000, 128] fp32

  // Workspace (int units), 35.9 MB (proven footprint). MhT aliases Xb2
  // (Xb2 dead after gemm_xw; MhT first written by edge_gemm).
  int* ws = (int*)d_ws;
  u64* Hbt             = (u64*)ws;                          // 1,600,000 u64
  u64* HbtT            = (u64*)(ws + 3200000);              // 313*5120 u64
  __hip_bfloat162* Xb2 = (__hip_bfloat162*)(ws + 6405120);  // 1,280,000 ints
  u16* MhT             = (u16*)(ws + 6405120);              // 128*5120 bf16 (alias)
  u16* WtB             = (u16*)(ws + 7685120);              // 16,384 bf16
  u16* XwT             = (u16*)(ws + 7693312);              // 128*20032 bf16
  // end: 8,975,360 ints = 35.9 MB

  scan_fused<<<1885, 256, 0, stream>>>(H, Hbt, HbtT, (const float2*)X, Xb2,
                                       W, WtB);
  gemm_xw   <<<626, 256, 0, stream>>>((const u16*)Xb2, WtB, XwT);
  edge_gemm <<<320, 256, 0, stream>>>(XwT, HbtT, MhT);
  node_gemm <<<313, 256, 0, stream>>>(Hbt, MhT, bias, out);
}

// Round 5
// 646.894 us; speedup vs baseline: 1.3887x; 1.1115x over previous
//
#include <hip/hip_runtime.h>
#include <hip/hip_bf16.h>

typedef unsigned long long u64;
typedef unsigned int u32;
typedef unsigned short u16;
typedef __attribute__((ext_vector_type(4))) float f32x4v;
typedef __attribute__((ext_vector_type(16))) float f32x16;
typedef __attribute__((ext_vector_type(8))) short bf16x8;  // 8 bf16 in 4 VGPRs

#define N_NODES 20000
#define N_EDGES 5000
#define FT 128
#define NT 20             // 256-col tiles per row in scan
#define NRG 313           // 64-row groups (last = 32 rows)
#define ROW_U64 80        // Hbt[n][w]: PLAIN bits, bit b <-> edge 64w+b
#define COL_STRIDE 5120   // HbtT[w][e]: bit b <-> node 64w+b (plain in n)
#define XWT_S 20032       // XwT row stride (20000 padded)

#define NTLOAD(p) __builtin_nontemporal_load((const f32x4v*)(p))

static __device__ __forceinline__ u64 spread4(u64 x) {  // bit i -> bit 4i (i<16)
  x = (x | (x << 24)) & 0x000000FF000000FFull;
  x = (x | (x << 12)) & 0x000F000F000F000Full;
  x = (x | (x << 6))  & 0x0303030303030303ull;
  x = (x | (x << 3))  & 0x1111111111111111ull;
  return x;
}

static __device__ __forceinline__ u16 f2bf(float x) {   // f32 -> bf16 rn
  u32 u = __float_as_uint(x);
  u = (u + 0x7FFFu + ((u >> 16) & 1u)) >> 16;
  return (u16)u;
}

// expand 8 H-bits -> 8 bf16 {0.0, 1.0}; element j <-> bit j. Pure VALU:
// runs on the per-SIMD pipe (x4 per CU) instead of the shared LDS pipe.
static __device__ __forceinline__ bf16x8 expand8(u32 b) {
  union { u32 u[4]; bf16x8 v; } r;
  r.u[0] = (( b        & 1u) | ((( b >> 1) & 1u) << 16)) * 0x3F80u;
  r.u[1] = (((b >> 2)  & 1u) | ((( b >> 3) & 1u) << 16)) * 0x3F80u;
  r.u[2] = (((b >> 4)  & 1u) | ((( b >> 5) & 1u) << 16)) * 0x3F80u;
  r.u[3] = (((b >> 6)  & 1u) | ((( b >> 7) & 1u) << 16)) * 0x3F80u;
  return r.v;
}

// LDS swizzle for [8 chunk][32 row] bf16x8 tiles: write side (vary c, fixed r)
// was 8-way bank-conflicted (c*512 B stride); XOR-rotate rows per chunk ->
// conflict-free writes, reads keep minimal 4-deep b128 pattern. u16 units.
static __device__ __forceinline__ int swz(int c, int r) {
  return c * 256 + (((r + c) & 31) << 3);
}

// ---------------------------------------------------------------------------
// Pass 1: NT-load ballot scan of H -> plain row bitmask Hbt + plain column
// bitmask HbtT, X->bf16 and W->bf16-transpose folded into tails. UNCHANGED.
__global__ __launch_bounds__(256) void scan_fused(
    const float* __restrict__ H, u64* __restrict__ Hbt, u64* __restrict__ HbtT,
    const float2* __restrict__ X2, __hip_bfloat162* __restrict__ Xb2,
    const float* __restrict__ Wf, u16* __restrict__ WtB) {
  const int wid = threadIdx.x >> 6, lane = threadIdx.x & 63;

  if (blockIdx.x >= 1565) {                    // folded tails
    for (int i = (blockIdx.x - 1565) * 256 + threadIdx.x; i < 1280000;
         i += 320 * 256)
      Xb2[i] = __float22bfloat162_rn(X2[i]);
    if (blockIdx.x == 1884) {                  // WtB[f][k] = bf16(W[k][f])
      for (int i = threadIdx.x; i < FT * FT; i += 256) {
        int f = i >> 7, k = i & 127;
        WtB[i] = f2bf(Wf[k * FT + f]);
      }
    }
    return;
  }

  const int gw = blockIdx.x * 4 + wid;         // 1565*4 = 6260 = NRG*NT
  const int t = gw % NT, rg = gw / NT;
  const int r0 = rg * 64;
  const int rows = min(64, N_NODES - r0);
  const int idx4 = t * 64 + lane;
  const bool lv = idx4 < 1250;

  u64 m0 = 0, m1 = 0, m2 = 0, m3 = 0;
  for (int kb = 0; kb < rows; kb += 8) {
    f32x4v vv[8];
#pragma unroll
    for (int k = 0; k < 8; ++k) vv[k] = (f32x4v){0.f, 0.f, 0.f, 0.f};
    if (lv) {
      const float* bp = H + (size_t)(r0 + kb) * N_EDGES + idx4 * 4;
#pragma unroll
      for (int k = 0; k < 8; ++k) vv[k] = NTLOAD(bp + (size_t)k * N_EDGES);
    }
#pragma unroll
    for (int k = 0; k < 8; ++k) {
      u64 b0 = __ballot(vv[k].x != 0.f);
      u64 b1 = __ballot(vv[k].y != 0.f);
      u64 b2 = __ballot(vv[k].z != 0.f);
      u64 b3 = __ballot(vv[k].w != 0.f);
      const bool keep = (lane == kb + k);
      m0 = keep ? b0 : m0;  m1 = keep ? b1 : m1;
      m2 = keep ? b2 : m2;  m3 = keep ? b3 : m3;
    }
  }
  if (lane < rows) {                           // de-interleave -> plain words
    u64* hp = Hbt + (size_t)(r0 + lane) * ROW_U64 + t * 4;
#pragma unroll
    for (int j = 0; j < 4; ++j) {
      u64 p = spread4((m0 >> (16 * j)) & 0xFFFFull)
            | (spread4((m1 >> (16 * j)) & 0xFFFFull) << 1)
            | (spread4((m2 >> (16 * j)) & 0xFFFFull) << 2)
            | (spread4((m3 >> (16 * j)) & 0xFFFFull) << 3);
      hp[j] = p;
    }
  }
  u64 t0 = 0, t1 = 0, t2 = 0, t3 = 0;          // 64x64 bit transpose
  for (int l = 0; l < 64; ++l) {
    u64 c0 = __ballot((m0 >> l) & 1ull);
    u64 c1 = __ballot((m1 >> l) & 1ull);
    u64 c2 = __ballot((m2 >> l) & 1ull);
    u64 c3 = __ballot((m3 >> l) & 1ull);
    const bool keep = (lane == l);
    t0 = keep ? c0 : t0;  t1 = keep ? c1 : t1;
    t2 = keep ? c2 : t2;  t3 = keep ? c3 : t3;
  }
  u64* op = HbtT + (size_t)rg * COL_STRIDE + t * 256 + 4 * lane;
  op[0] = t0; op[1] = t1; op[2] = t2; op[3] = t3;
}

// ---------------------------------------------------------------------------
// Pass 2: XwT[f][n] = bf16( (X @ W)[n][f] ).  MFMA 32x32x16: m=f, n=node,
// k=in-feat. X tile LDS-staged (coalesced, swizzled); W reads are L1-hot.
__global__ __launch_bounds__(256) void gemm_xw(
    const u16* __restrict__ Xb, const u16* __restrict__ WtB,
    u16* __restrict__ XwT) {
  __shared__ u16 xt[4096];                     // 8 KB: [32 n][16 kc] swizzled
  const int wave = threadIdx.x >> 6, lane = threadIdx.x & 63;
  const int col = lane & 31, half = lane >> 5;
  const int n0 = blockIdx.x * 32;
  const int f0 = wave * 32;
  if (n0 >= N_NODES) {                         // block 625: zero the pad cols
    if (lane < 32)
      for (int r = 0; r < 32; ++r)
        XwT[(size_t)(f0 + r) * XWT_S + n0 + lane] = 0;
    return;
  }
  {                                            // cooperative stage, coalesced
    const int sn = threadIdx.x >> 3, sc = threadIdx.x & 7;
#pragma unroll
    for (int j = 0; j < 2; ++j) {
      bf16x8 v = *(const bf16x8*)(Xb + (size_t)(n0 + sn) * FT + (sc + 8 * j) * 8);
      *(bf16x8*)(xt + sn * 128 + (((sc + 8 * j) + sn) & 15) * 8) = v;
    }
  }
  __syncthreads();
  f32x16 acc;
#pragma unroll
  for (int i = 0; i < 16; ++i) acc[i] = 0.f;
#pragma unroll
  for (int kc = 0; kc < 16; kc += 2) {
    int c = kc + half;
    bf16x8 a = *(const bf16x8*)(WtB + (f0 + col) * FT + c * 8);
    bf16x8 b = *(const bf16x8*)(xt + col * 128 + ((c + col) & 15) * 8);
    acc = __builtin_amdgcn_mfma_f32_32x32x16_bf16(a, b, acc, 0, 0, 0);
  }
#pragma unroll
  for (int r = 0; r < 16; ++r) {
    int fr = (r & 3) + 8 * (r >> 2) + 4 * half;   // D row (verified map)
    XwT[(size_t)(f0 + fr) * XWT_S + n0 + col] = f2bf(acc[r]);
  }
}

// ---------------------------------------------------------------------------
// Pass 3: MhT[f][e] = bf16( sum_n Xw[n][f]*H[n][e] / DE[e] ).
// Grid 640 = 160 e-tiles(32) x 4 f-tiles(32) -> 2.5 blocks/CU, 10 waves/CU.
// Waves k-split the 313 words {79,78,78,78}; per-wave swizzled LDS A-dbuf
// (barrier-free loop); B = VALU expand8; cross-wave LDS reduce + /DE.
__global__ __launch_bounds__(256) void edge_gemm(
    const u16* __restrict__ XwT, const u64* __restrict__ HbtT,
    u16* __restrict__ MhT) {
  __shared__ u16 atile[4][2][2048];  // 32 KB: per-wave dbuf [c8][f32] swizzled
  __shared__ float sdv[4][32];       // partial DE per wave
  const int tid = threadIdx.x;
  const int wid = tid >> 6, lane = tid & 63;
  const int col = lane & 31, half = lane >> 5;

  const int et = blockIdx.x % 160, ft = blockIdx.x / 160;
  const int e0 = et * 32, f0 = ft * 32;
  const int ws_ = wid * 78 + (wid > 0 ? 1 : 0);       // 0,79,157,235
  const int we_ = ws_ + (wid == 0 ? 79 : 78);         // 79,157,235,313

  // stage: instr j covers rows 8j..8j+7 fully coalesced (8 lanes/row)
  const int srow = lane >> 3, schunk = lane & 7;
  const u16* sgbase = XwT + (size_t)(f0 + srow) * XWT_S + schunk * 8;
  u16* buf0 = &atile[wid][0][0];
  u16* buf1 = &atile[wid][1][0];

  f32x16 acc;
#pragma unroll
  for (int i = 0; i < 16; ++i) acc[i] = 0.f;
  float dv = 0.f;

  {                                            // prologue: stage w=ws_
    bf16x8 st[4];
#pragma unroll
    for (int j = 0; j < 4; ++j)
      st[j] = *(const bf16x8*)(sgbase + (size_t)(8 * j) * XWT_S + ws_ * 64);
#pragma unroll
    for (int j = 0; j < 4; ++j)
      *(bf16x8*)(buf0 + swz(schunk, srow + 8 * j)) = st[j];
  }
  u64 wA = HbtT[(size_t)ws_ * COL_STRIDE + e0 + col];

  int p = 0;
  for (int w = ws_; w < we_; ++w) {
    const int wn = (w + 1 < we_) ? w + 1 : w;
    bf16x8 nst[4];                             // prefetch next tile to regs
#pragma unroll
    for (int j = 0; j < 4; ++j)
      nst[j] = *(const bf16x8*)(sgbase + (size_t)(8 * j) * XWT_S + wn * 64);
    u64 nA = HbtT[(size_t)wn * COL_STRIDE + e0 + col];

    const u16* ab = p ? buf1 : buf0;           // compute current
#pragma unroll
    for (int q = 0; q < 4; ++q) {
      bf16x8 a = *(const bf16x8*)(ab + swz(2 * q + half, col));
      bf16x8 b = expand8((u32)(wA >> (q * 16 + half * 8)) & 0xFFu);
      acc = __builtin_amdgcn_mfma_f32_32x32x16_bf16(a, b, acc, 0, 0, 0);
    }
    dv += (float)__popcll(wA);

    u16* nb = p ? buf0 : buf1;                 // write-late (T14)
#pragma unroll
    for (int j = 0; j < 4; ++j)
      *(bf16x8*)(nb + swz(schunk, srow + 8 * j)) = nst[j];
    wA = nA; p ^= 1;
  }

  // dump acc into own atile region (reused as 1024-f32 scratch per wave)
  float* sacc = (float*)&atile[wid][0][0];
#pragma unroll
  for (int r = 0; r < 16; ++r) {
    int fr = (r & 3) + 8 * (r >> 2) + 4 * half;
    sacc[fr * 32 + col] = acc[r];
  }
  if (half == 0) sdv[wid][col] = dv;
  __syncthreads();

  {                                            // cross-wave reduce + /DE + bf16
    const int frl = tid >> 3, eq = tid & 7;    // 32 f-rows x 8 e-quads
    const float* s0 = (const float*)&atile[0][0][0];
    union { u16 h[4]; u64 q; } o;
#pragma unroll
    for (int j = 0; j < 4; ++j) {
      int e = eq * 4 + j;
      int idx = frl * 32 + e;
      float s = s0[idx] + s0[2048 + idx] + s0[4096 + idx] + s0[6144 + idx];
      float d = sdv[0][e] + sdv[1][e] + sdv[2][e] + sdv[3][e];
      o.h[j] = f2bf(s / (d + 1e-12f));
    }
    *(u64*)(MhT + (size_t)(f0 + frl) * COL_STRIDE + e0 + eq * 4) = o.q;
  }
}

// ---------------------------------------------------------------------------
// Pass 4: out[n][f] = relu( (H @ M)[n][f] / DV[n] + bias[f] ).
// Grid 625 x 4 f-waves (9.8 waves/CU), each wave independent 32n x 32f:
// own swizzled LDS B-dbuf (zero barriers), A = VALU expand8 of Hbt words.
__global__ __launch_bounds__(256) void node_gemm(
    const u64* __restrict__ Hbt, const u16* __restrict__ MhT,
    const float* __restrict__ bias, float* __restrict__ out) {
  __shared__ u16 btile[4][2][2048];  // 32 KB: per-wave dbuf [c8][f32] swizzled
  const int tid = threadIdx.x;
  const int wid = tid >> 6, lane = tid & 63;
  const int col = lane & 31, half = lane >> 5;
  const int n0 = blockIdx.x * 32;
  const int f0 = wid * 32;

  // stage: instr j covers f-rows 8j..8j+7 coalesced (8 lanes/row)
  const int srow = lane >> 3, schunk = lane & 7;
  const u16* sgbase = MhT + (size_t)(f0 + srow) * COL_STRIDE + schunk * 8;
  u16* buf0 = &btile[wid][0][0];
  u16* buf1 = &btile[wid][1][0];

  f32x16 acc;
#pragma unroll
  for (int i = 0; i < 16; ++i) acc[i] = 0.f;

  {                                            // prologue: stage w=0
    bf16x8 st[4];
#pragma unroll
    for (int j = 0; j < 4; ++j)
      st[j] = *(const bf16x8*)(sgbase + (size_t)(8 * j) * COL_STRIDE);
#pragma unroll
    for (int j = 0; j < 4; ++j)
      *(bf16x8*)(buf0 + swz(schunk, srow + 8 * j)) = st[j];
  }
  u64 word = Hbt[(size_t)(n0 + col) * ROW_U64];
  float dv = 0.f;

  int p = 0;
  for (int w = 0; w < ROW_U64; ++w) {
    const int wn = (w + 1 < ROW_U64) ? w + 1 : w;
    bf16x8 nst[4];                             // prefetch next e-slice
#pragma unroll
    for (int j = 0; j < 4; ++j)
      nst[j] = *(const bf16x8*)(sgbase + (size_t)(8 * j) * COL_STRIDE + wn * 64);
    u64 nword = Hbt[(size_t)(n0 + col) * ROW_U64 + wn];

    const u16* bb = p ? buf1 : buf0;           // compute current
#pragma unroll
    for (int q = 0; q < 4; ++q) {
      bf16x8 a = expand8((u32)(word >> (q * 16 + half * 8)) & 0xFFu);
      bf16x8 b = *(const bf16x8*)(bb + swz(2 * q + half, col));
      acc = __builtin_amdgcn_mfma_f32_32x32x16_bf16(a, b, acc, 0, 0, 0);
    }
    dv += (float)__popcll(word);

    u16* nb = p ? buf0 : buf1;                 // write-late (T14)
#pragma unroll
    for (int j = 0; j < 4; ++j)
      *(bf16x8*)(nb + swz(schunk, srow + 8 * j)) = nst[j];
    word = nword; p ^= 1;
  }

  float inv = 1.f / (dv + 1e-12f);             // lanes 0..31: col <-> node
  float bb = bias[f0 + col];
#pragma unroll
  for (int r = 0; r < 16; ++r) {
    int rr = (r & 3) + 8 * (r >> 2) + 4 * half;    // D row = node-local
    float iv = __shfl(inv, rr);
    out[(size_t)(n0 + rr) * FT + f0 + col] = fmaxf(fmaf(acc[r], iv, bb), 0.f);
  }
}

extern "C" void kernel_launch(void* const* d_in, const int* in_sizes, int n_in,
                              void* d_out, int out_size, void* d_ws, size_t ws_size,
                              hipStream_t stream) {
  const float* X    = (const float*)d_in[0];   // [20000, 128]
  const float* H    = (const float*)d_in[1];   // [20000, 5000] dense 0/1
  const float* W    = (const float*)d_in[2];   // [128, 128]
  const float* bias = (const float*)d_in[3];   // [128]
  float* out = (float*)d_out;                  // [20000, 128] fp32

  // Workspace (int units), 35.9 MB (proven footprint). MhT aliases Xb2
  // (Xb2 dead after gemm_xw; MhT first written by edge_gemm).
  int* ws = (int*)d_ws;
  u64* Hbt             = (u64*)ws;                          // 1,600,000 u64
  u64* HbtT            = (u64*)(ws + 3200000);              // 313*5120 u64
  __hip_bfloat162* Xb2 = (__hip_bfloat162*)(ws + 6405120);  // 1,280,000 ints
  u16* MhT             = (u16*)(ws + 6405120);              // 128*5120 bf16 (alias)
  u16* WtB             = (u16*)(ws + 7685120);              // 16,384 bf16
  u16* XwT             = (u16*)(ws + 7693312);              // 128*20032 bf16
  // end: 8,975,360 ints = 35.9 MB

  scan_fused<<<1885, 256, 0, stream>>>(H, Hbt, HbtT, (const float2*)X, Xb2,
                                       W, WtB);
  gemm_xw   <<<626, 256, 0, stream>>>((const u16*)Xb2, WtB, XwT);
  edge_gemm <<<640, 256, 0, stream>>>(XwT, HbtT, MhT);
  node_gemm <<<625, 256, 0, stream>>>(Hbt, MhT, bias, out);
}